// Round 5
// baseline (336.638 us; speedup 1.0000x reference)
//
#include <hip/hip_runtime.h>

// Problem constants (from reference)
#define B_    4
#define S_    2048
#define V_    50257
#define NB_   32
#define BS_   (B_ * S_)            // 8192 rows
#define TEMP_ 0.07f

static_assert((long long)BS_ * V_ % 4 == 0, "flat onehot must be float4-divisible");

typedef int i4 __attribute__((ext_vector_type(4)));

// ---------------------------------------------------------------------------
// Kernel 1: streaming scan. Lean hit path: write tid[row]=col only.
// Inputs are exact 0.0f/1.0f -> integer-bit nonzero test is safe.
// ---------------------------------------------------------------------------
__device__ __forceinline__ void check_vec(i4 u, long long idx4,
                                          int* __restrict__ tid)
{
    if (__builtin_expect((u.x | u.y | u.z | u.w) != 0, 0)) {
        long long base = idx4 * 4;
        #pragma unroll
        for (int k = 0; k < 4; ++k) {
            int uk = (k == 0) ? u.x : (k == 1) ? u.y : (k == 2) ? u.z : u.w;
            if (uk != 0) {
                long long idx = base + k;
                int row = (int)(idx / V_);            // magic-mul
                int col = (int)(idx - (long long)row * V_);
                tid[row] = col;
            }
        }
    }
}

__global__ __launch_bounds__(256, 8) void find_tokens_kernel(
    const i4* __restrict__ onehot4, int* __restrict__ tid)
{
    const long long n4 = (long long)BS_ * V_ / 4;   // 102,926,336
    const long long stride = (long long)gridDim.x * blockDim.x;
    long long i = (long long)blockIdx.x * blockDim.x + threadIdx.x;

    // ILP=4: four plain (cached) loads in flight per thread,
    // stride-separated so each instruction stays fully coalesced.
    for (; i + 3 * stride < n4; i += 4 * stride) {
        i4 a = onehot4[i];
        i4 b = onehot4[i + stride];
        i4 c = onehot4[i + 2 * stride];
        i4 d = onehot4[i + 3 * stride];
        check_vec(a, i,              tid);
        check_vec(b, i + stride,     tid);
        check_vec(c, i + 2 * stride, tid);
        check_vec(d, i + 3 * stride, tid);
    }
    for (; i < n4; i += stride) {
        i4 a = onehot4[i];
        check_vec(a, i, tid);
    }
}

// ---------------------------------------------------------------------------
// Kernel 2: per row, gather prototypes[n, tid], add gumbel, softmax(32),
// straight-through hard one-hot. One thread per row, all in registers.
// ---------------------------------------------------------------------------
__global__ __launch_bounds__(256) void gumbel_hard_kernel(
    const float* __restrict__ proto,     // [NB, V]
    const float* __restrict__ gumbel,    // [BS, NB]
    const int*   __restrict__ tid,       // [BS]
    float*       __restrict__ out)       // [BS, NB]
{
    int row = blockIdx.x * blockDim.x + threadIdx.x;
    if (row >= BS_) return;
    int t = tid[row];

    float g[NB_];
    {
        const float4* g4 = reinterpret_cast<const float4*>(gumbel + (long long)row * NB_);
        #pragma unroll
        for (int q = 0; q < NB_ / 4; ++q) {
            float4 v = g4[q];
            g[q * 4 + 0] = v.x; g[q * 4 + 1] = v.y;
            g[q * 4 + 2] = v.z; g[q * 4 + 3] = v.w;
        }
    }

    float z[NB_];
    float m = -1e30f;
    int   am = 0;
    #pragma unroll
    for (int n = 0; n < NB_; ++n) {
        float s = proto[(long long)n * V_ + t];
        float zn = s / TEMP_ + g[n];
        z[n] = zn;
        if (zn > m) { m = zn; am = n; }   // strict > => first max (matches argmax)
    }

    float e[NB_];
    float sum = 0.0f;
    #pragma unroll
    for (int n = 0; n < NB_; ++n) {
        e[n] = __expf(z[n] - m);
        sum += e[n];
    }
    float inv = 1.0f / sum;

    float4* o4 = reinterpret_cast<float4*>(out + (long long)row * NB_);
    #pragma unroll
    for (int q = 0; q < NB_ / 4; ++q) {
        float4 v; float r[4];
        #pragma unroll
        for (int k = 0; k < 4; ++k) {
            int n = q * 4 + k;
            float y = e[n] * inv;
            float h = (n == am) ? 1.0f : 0.0f;
            r[k] = (h - y) + y;           // reproduce straight-through arithmetic
        }
        v.x = r[0]; v.y = r[1]; v.z = r[2]; v.w = r[3];
        o4[q] = v;
    }
}

extern "C" void kernel_launch(void* const* d_in, const int* in_sizes, int n_in,
                              void* d_out, int out_size, void* d_ws, size_t ws_size,
                              hipStream_t stream)
{
    const float* onehot = (const float*)d_in[0];   // [B,S,V] f32
    const float* proto  = (const float*)d_in[1];   // [NB,V] f32
    const float* gumbel = (const float*)d_in[2];   // [B,S,NB] f32
    float* out = (float*)d_out;                    // [B,S,NB] f32
    int* tid = (int*)d_ws;                         // 8192 ints scratch

    // 4096 blocks x 256 (R1's grid) — two scheduling rounds, good DRAM window
    find_tokens_kernel<<<4096, 256, 0, stream>>>(
        reinterpret_cast<const i4*>(onehot), tid);

    gumbel_hard_kernel<<<(BS_ + 255) / 256, 256, 0, stream>>>(
        proto, gumbel, tid, out);
}

// Round 6
// 271.530 us; speedup vs baseline: 1.2398x; 1.2398x over previous
//
#include <hip/hip_runtime.h>

// Problem constants (from reference)
#define B_    4
#define S_    2048
#define V_    50257
#define NB_   32
#define BS_   (B_ * S_)            // 8192 rows
#define TEMP_ 0.07f

static_assert((long long)BS_ * V_ % 4 == 0, "flat onehot must be float4-divisible");

typedef int i4 __attribute__((ext_vector_type(4)));

// ---------------------------------------------------------------------------
// Kernel 1: streaming scan — R1 structure (ILP1 grid-stride, one sliding
// window) + nontemporal loads (don't allocate dead lines in L2/L3).
// Inputs are exact 0.0f/1.0f -> integer-bit nonzero test is safe.
// ---------------------------------------------------------------------------
__global__ __launch_bounds__(256) void find_tokens_kernel(
    const i4* __restrict__ onehot4, int* __restrict__ tid)
{
    const long long n4 = (long long)BS_ * V_ / 4;   // 102,926,336
    const long long stride = (long long)gridDim.x * blockDim.x;
    long long i = (long long)blockIdx.x * blockDim.x + threadIdx.x;

    for (; i < n4; i += stride) {
        i4 u = __builtin_nontemporal_load(&onehot4[i]);
        if (__builtin_expect((u.x | u.y | u.z | u.w) != 0, 0)) {
            long long base = i * 4;
            #pragma unroll
            for (int k = 0; k < 4; ++k) {
                int uk = (k == 0) ? u.x : (k == 1) ? u.y : (k == 2) ? u.z : u.w;
                if (uk != 0) {
                    long long idx = base + k;
                    int row = (int)(idx / V_);            // magic-mul
                    int col = (int)(idx - (long long)row * V_);
                    tid[row] = col;
                }
            }
        }
    }
}

// ---------------------------------------------------------------------------
// Kernel 2: per row, gather prototypes[n, tid], add gumbel, softmax(32),
// straight-through hard one-hot. One thread per row, all in registers.
// ---------------------------------------------------------------------------
__global__ __launch_bounds__(256) void gumbel_hard_kernel(
    const float* __restrict__ proto,     // [NB, V]
    const float* __restrict__ gumbel,    // [BS, NB]
    const int*   __restrict__ tid,       // [BS]
    float*       __restrict__ out)       // [BS, NB]
{
    int row = blockIdx.x * blockDim.x + threadIdx.x;
    if (row >= BS_) return;
    int t = tid[row];

    float g[NB_];
    {
        const float4* g4 = reinterpret_cast<const float4*>(gumbel + (long long)row * NB_);
        #pragma unroll
        for (int q = 0; q < NB_ / 4; ++q) {
            float4 v = g4[q];
            g[q * 4 + 0] = v.x; g[q * 4 + 1] = v.y;
            g[q * 4 + 2] = v.z; g[q * 4 + 3] = v.w;
        }
    }

    float z[NB_];
    float m = -1e30f;
    int   am = 0;
    #pragma unroll
    for (int n = 0; n < NB_; ++n) {
        float s = proto[(long long)n * V_ + t];
        float zn = s / TEMP_ + g[n];
        z[n] = zn;
        if (zn > m) { m = zn; am = n; }   // strict > => first max (matches argmax)
    }

    float e[NB_];
    float sum = 0.0f;
    #pragma unroll
    for (int n = 0; n < NB_; ++n) {
        e[n] = __expf(z[n] - m);
        sum += e[n];
    }
    float inv = 1.0f / sum;

    float4* o4 = reinterpret_cast<float4*>(out + (long long)row * NB_);
    #pragma unroll
    for (int q = 0; q < NB_ / 4; ++q) {
        float4 v; float r[4];
        #pragma unroll
        for (int k = 0; k < 4; ++k) {
            int n = q * 4 + k;
            float y = e[n] * inv;
            float h = (n == am) ? 1.0f : 0.0f;
            r[k] = (h - y) + y;           // reproduce straight-through arithmetic
        }
        v.x = r[0]; v.y = r[1]; v.z = r[2]; v.w = r[3];
        o4[q] = v;
    }
}

extern "C" void kernel_launch(void* const* d_in, const int* in_sizes, int n_in,
                              void* d_out, int out_size, void* d_ws, size_t ws_size,
                              hipStream_t stream)
{
    const float* onehot = (const float*)d_in[0];   // [B,S,V] f32
    const float* proto  = (const float*)d_in[1];   // [NB,V] f32
    const float* gumbel = (const float*)d_in[2];   // [B,S,NB] f32
    float* out = (float*)d_out;                    // [B,S,NB] f32
    int* tid = (int*)d_ws;                         // 8192 ints scratch

    find_tokens_kernel<<<4096, 256, 0, stream>>>(
        reinterpret_cast<const i4*>(onehot), tid);

    gumbel_hard_kernel<<<(BS_ + 255) / 256, 256, 0, stream>>>(
        proto, gumbel, tid, out);
}